// Round 10
// baseline (199.184 us; speedup 1.0000x reference)
//
#include <hip/hip_runtime.h>

#define B_ROWS 4096
#define T_LEN  2048
#define TB     16                 // timesteps per register block
#define NBLK   (T_LEN / TB)       // 128 (even)

// ---- DPP quad reduce (builtins only; fusion abandoned after R3/R5/R6/R8/R9)
template<int CTRL>
__device__ __forceinline__ float dpp_add(float x) {
  int y = __builtin_amdgcn_mov_dpp(__builtin_bit_cast(int, x),
                                   CTRL, 0xf, 0xf, true);
  return x + __builtin_bit_cast(float, y);
}
// Sum across the 4 lanes of a DPP quad (each row owns exactly one quad).
__device__ __forceinline__ float quad_allreduce(float x) {
  x = dpp_add<0xB1>(x);    // quad_perm [1,0,3,2] : xor 1
  x = dpp_add<0x4E>(x);    // quad_perm [2,3,0,1] : xor 2
  return x;
}

// One register block: 16 timesteps of (eps,hs) for THIS lane's row.
struct Blk { float4 q[8]; };

__device__ __forceinline__ void load_blk(const float4* __restrict__ src,
                                         Blk& b) {
#pragma unroll
  for (int i = 0; i < 8; ++i) b.q[i] = src[i];   // 4-lane broadcast per quad
}

// 16 steps, z-form (z = -log2e*z1, per unit).  CHAIN per step (10 ops):
//   exp2 -> d-fma -> rcp -> add -> add -> movdpp -> add -> movdpp -> add -> z'fma
// Everything else (P, hw, s0 path, latch) is off-chain issue work.
__device__ __forceinline__ void compute16(
    const Blk& bk, float nextq0x, bool peek, float4& z,
    const float4 w0n, const float4 w1n, const float4 invc1,
    const float4 ratio, int q, float* __restrict__ outp) {
  float4 kp = make_float4(0.f, 0.f, 0.f, 0.f);
#pragma unroll
  for (int t = 0; t < TB; ++t) {
    const float eps  = (t & 1) ? bk.q[t >> 1].z : bk.q[t >> 1].x;
    const float hs   = (t & 1) ? bk.q[t >> 1].w : bk.q[t >> 1].y;
    const float epsn = (t == TB - 1) ? (peek ? nextq0x : eps)
                       : ((t & 1) ? bk.q[(t + 1) >> 1].x : bk.q[t >> 1].z);
    // ---- chain: 4 parallel sigmoid pipes (per-unit), then reduce ----
    float e0 = __builtin_amdgcn_exp2f(z.x);
    float e1 = __builtin_amdgcn_exp2f(z.y);
    float e2 = __builtin_amdgcn_exp2f(z.z);
    float e3 = __builtin_amdgcn_exp2f(z.w);
    float r0 = __builtin_amdgcn_rcpf(fmaf(e0, invc1.x, invc1.x)); // c1*sig
    float r1 = __builtin_amdgcn_rcpf(fmaf(e1, invc1.y, invc1.y));
    float r2 = __builtin_amdgcn_rcpf(fmaf(e2, invc1.z, invc1.z));
    float r3 = __builtin_amdgcn_rcpf(fmaf(e3, invc1.w, invc1.w));
    float s1 = quad_allreduce((r0 + r1) + (r2 + r3));   // gamma-path sum
    // ---- off-chain: P = z + deps*w0n (z-recurrence), hw = -hs*w1n ----
    float deps = epsn - eps;
    float P0 = fmaf(deps, w0n.x, z.x);
    float P1 = fmaf(deps, w0n.y, z.y);
    float P2 = fmaf(deps, w0n.z, z.z);
    float P3 = fmaf(deps, w0n.w, z.w);
    float hn = -hs;
    z.x = fmaf(hn * w1n.x, s1, P0);                     // chain tail (1 op)
    z.y = fmaf(hn * w1n.y, s1, P1);
    z.z = fmaf(hn * w1n.z, s1, P2);
    z.w = fmaf(hn * w1n.w, s1, P3);
    // ---- off-chain: output path ----
    float s0 = quad_allreduce(fmaf(r0, ratio.x, r1 * ratio.y) +
                              fmaf(r2, ratio.z, r3 * ratio.w));
    const bool mine = ((t >> 2) == q);    // lane q keeps t in [4q, 4q+4)
    if ((t & 3) == 0) kp.x = mine ? s0 : kp.x;
    if ((t & 3) == 1) kp.y = mine ? s0 : kp.y;
    if ((t & 3) == 2) kp.z = mine ? s0 : kp.z;
    if ((t & 3) == 3) kp.w = mine ? s0 : kp.w;
  }
  *(float4*)(outp + 4 * q) = kp;   // coalesced 16B store per lane
}

__global__ __launch_bounds__(64) void gsm_scan_kernel(
    const float* __restrict__ inp, const float* __restrict__ W1f,
    const float* __restrict__ b1f, const float* __restrict__ W2f,
    float* __restrict__ out) {
  const int lane = threadIdx.x;       // 0..63
  const int q    = lane & 3;          // unit-group within row (DPP quad slot)
  const int row  = (blockIdx.x << 4) + (lane >> 2);   // 16 rows per wave
  const int u0   = q << 2;            // this lane's 4 hidden units: u0..u0+3

  const float LOG2E = 1.4426950408889634f;
  const float4 W0 = *(const float4*)&W1f[u0];        // W1[0, u0..u0+3]
  const float4 Wr = *(const float4*)&W1f[16 + u0];   // W1[1, u0..u0+3]
  const float4 B1 = *(const float4*)&b1f[u0];
  const float4 W2 = *(const float4*)&W2f[u0];

  float4 w0n, w1n, bnn, invc1, ratio;
  w0n.x = -LOG2E * W0.x; w0n.y = -LOG2E * W0.y;
  w0n.z = -LOG2E * W0.z; w0n.w = -LOG2E * W0.w;
  w1n.x = -LOG2E * Wr.x; w1n.y = -LOG2E * Wr.y;
  w1n.z = -LOG2E * Wr.z; w1n.w = -LOG2E * Wr.w;
  bnn.x = -LOG2E * B1.x; bnn.y = -LOG2E * B1.y;
  bnn.z = -LOG2E * B1.z; bnn.w = -LOG2E * B1.w;
  // c1_u = 0.1*w2_u*W1[1,u] (gamma path); c0_u = w2_u*W1[0,u] (output path)
  invc1.x = 1.0f / (0.1f * W2.x * Wr.x);  ratio.x = (W2.x * W0.x) * invc1.x * 0.0f + (W2.x * W0.x) * (0.1f * W2.x * Wr.x == 0.f ? 0.f : 1.0f / (0.1f * W2.x * Wr.x));
  // (simplified below — compute cleanly)
  invc1.x = 1.0f / (0.1f * W2.x * Wr.x);
  invc1.y = 1.0f / (0.1f * W2.y * Wr.y);
  invc1.z = 1.0f / (0.1f * W2.z * Wr.z);
  invc1.w = 1.0f / (0.1f * W2.w * Wr.w);
  ratio.x = (W2.x * W0.x) * invc1.x;      // c0/c1
  ratio.y = (W2.y * W0.y) * invc1.y;
  ratio.z = (W2.z * W0.z) * invc1.z;
  ratio.w = (W2.w * W0.w) * invc1.w;

  const float4* src = (const float4*)(inp + (size_t)row * (2 * T_LEN));
  float* outrow = out + (size_t)row * T_LEN;

  Blk A, Bb;
  load_blk(src, A);                  // block 0
  load_blk(src + 8, Bb);             // block 1
  // z0_u = eps0*w0n_u + bnn_u   (gamma0 = 0)
  float4 z;
  z.x = fmaf(A.q[0].x, w0n.x, bnn.x);
  z.y = fmaf(A.q[0].x, w0n.y, bnn.y);
  z.z = fmaf(A.q[0].x, w0n.z, bnn.z);
  z.w = fmaf(A.q[0].x, w0n.w, bnn.w);

#pragma unroll 1
  for (int b = 0; b < NBLK; b += 2) {
    // ---- phase 1: block b from A; prefetch b+2 into A's (now dead) regs
    Blk cur = A;
    if (b + 2 < NBLK) load_blk(src + (size_t)(b + 2) * 8, A);
    compute16(cur, Bb.q[0].x, true, z, w0n, w1n, invc1, ratio, q,
              outrow + b * TB);
    // ---- phase 2: block b+1 from Bb; prefetch b+3 into Bb's regs
    Blk cur2 = Bb;
    if (b + 3 < NBLK) load_blk(src + (size_t)(b + 3) * 8, Bb);
    compute16(cur2, A.q[0].x, (b + 2 < NBLK), z, w0n, w1n, invc1, ratio, q,
              outrow + (b + 1) * TB);
  }
}

extern "C" void kernel_launch(void* const* d_in, const int* in_sizes, int n_in,
                              void* d_out, int out_size, void* d_ws,
                              size_t ws_size, hipStream_t stream) {
  const float* inp = (const float*)d_in[0];   // (B, T, 2) f32
  const float* W1  = (const float*)d_in[1];   // (2, 16)
  const float* b1  = (const float*)d_in[2];   // (16,)
  const float* W2  = (const float*)d_in[3];   // (16, 1)
  // d_in[4] = b2 : unused by the reference computation
  float* out = (float*)d_out;                 // (B, T) f32

  dim3 grid(B_ROWS / 16);  // 256 waves, 16 rows/wave, 4 lanes/row;
  dim3 block(64);          // wall = 2048 steps x chain, chain is the lever
  hipLaunchKernelGGL(gsm_scan_kernel, grid, block, 0, stream,
                     inp, W1, b1, W2, out);
}

// Round 11
// 125.260 us; speedup vs baseline: 1.5902x; 1.5902x over previous
//
#include <hip/hip_runtime.h>
#include <cmath>

#define B_ROWS 4096
#define T_LEN  2048
#define TB     16                 // timesteps per register block
#define NBLK   (T_LEN / TB)       // 128 (even)

// ---- DPP butterfly via builtins (R2/R4/R7-proven; asm + fusion abandoned)
template<int CTRL>
__device__ __forceinline__ float dpp_add(float x) {
  int y = __builtin_amdgcn_mov_dpp(__builtin_bit_cast(int, x),
                                   CTRL, 0xf, 0xf, true);
  return x + __builtin_bit_cast(float, y);
}
__device__ __forceinline__ float allreduce16(float x) {
  x = dpp_add<0xB1>(x);    // xor 1
  x = dpp_add<0x4E>(x);    // xor 2
  x = dpp_add<0x141>(x);   // row_half_mirror (xor within 8, valid as stage 3)
  x = dpp_add<0x140>(x);   // row_mirror      (valid as stage 4)
  return x;
}

struct Coef { float a[8]; float K; };   // sigma(u) ~ 0.5 + u*q(u^2), |u|<=K

// One register block: 16 timesteps of (eps,hs) = 8 float4 = 32 VGPRs.
struct Blk { float4 q[8]; };

__device__ __forceinline__ void load_blk(const float4* __restrict__ src,
                                         Blk& b) {
#pragma unroll
  for (int i = 0; i < 8; ++i) b.q[i] = src[i];   // broadcast within 16 lanes
}

struct Pre { float dpre[TB - 1]; float hwn[TB]; float eps15; };

__device__ __forceinline__ void extract(const Blk& b, float w0j, float w1j,
                                        Pre& p) {
  float eps[TB];
#pragma unroll
  for (int i = 0; i < 8; ++i) {
    eps[2 * i]       = b.q[i].x;
    p.hwn[2 * i]     = -b.q[i].y * w1j;
    eps[2 * i + 1]   = b.q[i].z;
    p.hwn[2 * i + 1] = -b.q[i].w * w1j;
  }
#pragma unroll
  for (int t = 0; t < TB - 1; ++t) p.dpre[t] = (eps[t + 1] - eps[t]) * w0j;
  p.eps15 = eps[TB - 1];
}

// 16 steps, u-form (u = z1, plain). CHAIN per step (~79 cy, NO trans ops):
//   u'fma -> med3 -> u^2 -> Estrin L1 -> L2 -> L3 -> v1 fma -> butterfly(8)
__device__ __forceinline__ void compute16(const Pre& p, float nextq0x,
                                          bool peek, float& u, const Coef cf,
                                          float w0j, float c0j, float c1j,
                                          float h0, float h1, int j,
                                          float* __restrict__ outp) {
  float keep = 0.0f;
#pragma unroll
  for (int t = 0; t < TB; ++t) {
    float uc  = __builtin_amdgcn_fmed3f(u, -cf.K, cf.K);   // clamp (1 op)
    float u2  = uc * uc;
    float c1u = c1j * uc;                  // parallel with u2
    float c0u = c0j * uc;
    float b0 = fmaf(cf.a[1], u2, cf.a[0]);
    float b1 = fmaf(cf.a[3], u2, cf.a[2]);
    float b2 = fmaf(cf.a[5], u2, cf.a[4]);
    float b3 = fmaf(cf.a[7], u2, cf.a[6]);
    float u4 = u2 * u2;
    float d0 = fmaf(b1, u4, b0);
    float d1 = fmaf(b3, u4, b2);
    float u8 = u4 * u4;
    float q  = fmaf(d1, u8, d0);           // q(u^2)
    float v1 = fmaf(c1u, q, h1);           // c1 * sigma  (chain)
    float v0 = fmaf(c0u, q, h0);           // c0 * sigma  (off-chain)
    float s1 = allreduce16(v1);            // gamma-path sum (chain)
    float s0 = allreduce16(v0);            // output sum (off-chain)
    float dpre_t = (t < TB - 1)
                     ? p.dpre[t]
                     : (peek ? ((nextq0x - p.eps15) * w0j) : 0.0f);
    float P = u + dpre_t;                  // off-chain
    u    = fmaf(p.hwn[t], s1, P);          // u' (chain tail)
    keep = (j == t) ? s0 : keep;           // branchless latch
  }
  outp[j] = keep;   // 16 consecutive floats per row per block
}

__global__ __launch_bounds__(64) void gsm_scan_kernel(
    const float* __restrict__ inp, const float* __restrict__ W1f,
    const float* __restrict__ b1f, const float* __restrict__ W2f,
    float* __restrict__ out, const Coef cf) {
  const int lane = threadIdx.x;       // 0..63
  const int grp  = lane >> 4;         // row within wave, 0..3
  const int j    = lane & 15;         // hidden unit
  const int row  = (blockIdx.x << 2) + grp;

  const float w0j = W1f[j];
  const float w1j = W1f[16 + j];
  const float bj  = b1f[j];
  const float w2j = W2f[j];
  const float c0j = w2j * w0j;          // output-path coefficient
  const float c1j = 0.1f * w2j * w1j;   // gamma-path coeff (inv_eta folded)
  const float h0  = 0.5f * c0j;
  const float h1  = 0.5f * c1j;

  const float4* src = (const float4*)(inp + (size_t)row * (2 * T_LEN));
  float* outrow = out + (size_t)row * T_LEN;

  Blk A, Bb;
  Pre p;
  load_blk(src, A);                  // block 0
  load_blk(src + 8, Bb);             // block 1
  float u = fmaf(A.q[0].x, w0j, bj);   // u0 = eps0*w0 + b  (gamma0 = 0)

#pragma unroll 1
  for (int b = 0; b < NBLK; b += 2) {
    // ---- phase 1: block b from A; prefetch b+2 into A's (now dead) regs
    extract(A, w0j, w1j, p);
    if (b + 2 < NBLK) load_blk(src + (size_t)(b + 2) * 8, A);
    compute16(p, Bb.q[0].x, true, u, cf, w0j, c0j, c1j, h0, h1, j,
              outrow + b * TB);
    // ---- phase 2: block b+1 from Bb; prefetch b+3 into Bb's regs
    extract(Bb, w0j, w1j, p);
    if (b + 3 < NBLK) load_blk(src + (size_t)(b + 3) * 8, Bb);
    compute16(p, A.q[0].x, (b + 2 < NBLK), u, cf, w0j, c0j, c1j, h0, h1, j,
              outrow + (b + 1) * TB);
  }
}

// ---- host-side: LS fit of sigma(u)-0.5 with odd poly, deg 15, on [-K,K] ----
static void fit_sigma_coeffs(double K, Coef& cf) {
  const int N = 1024;
  double M[8][8] = {{0}}, bv[8] = {0}, a[8];
  for (int i = 0; i < N; ++i) {
    double th = 3.14159265358979323846 * (i + 0.5) / (2.0 * N);
    double s  = cos(th);                 // Chebyshev-clustered in (0,1]
    double u  = K * s;
    double f  = 1.0 / (1.0 + exp(-u)) - 0.5;
    double pk[8]; double sp = s;
    for (int k = 0; k < 8; ++k) { pk[k] = sp; sp *= s * s; }
    for (int r = 0; r < 8; ++r) {
      bv[r] += f * pk[r];
      for (int c = 0; c < 8; ++c) M[r][c] += pk[r] * pk[c];
    }
  }
  for (int col = 0; col < 8; ++col) {         // Gauss, partial pivoting
    int piv = col;
    for (int r = col + 1; r < 8; ++r)
      if (fabs(M[r][col]) > fabs(M[piv][col])) piv = r;
    if (piv != col) {
      for (int c = 0; c < 8; ++c) { double t = M[col][c]; M[col][c] = M[piv][c]; M[piv][c] = t; }
      double t = bv[col]; bv[col] = bv[piv]; bv[piv] = t;
    }
    for (int r = col + 1; r < 8; ++r) {
      double fac = M[r][col] / M[col][col];
      for (int c = col; c < 8; ++c) M[r][c] -= fac * M[col][c];
      bv[r] -= fac * bv[col];
    }
  }
  for (int r = 7; r >= 0; --r) {
    double s2 = bv[r];
    for (int c = r + 1; c < 8; ++c) s2 -= M[r][c] * a[c];
    a[r] = s2 / M[r][r];
  }
  double Kp = K;                              // rescale s=u/K -> monomials in u
  for (int k = 0; k < 8; ++k) { cf.a[k] = (float)(a[k] / Kp); Kp *= K * K; }
  cf.K = (float)K;
}

extern "C" void kernel_launch(void* const* d_in, const int* in_sizes, int n_in,
                              void* d_out, int out_size, void* d_ws,
                              size_t ws_size, hipStream_t stream) {
  const float* inp = (const float*)d_in[0];   // (B, T, 2) f32
  const float* W1  = (const float*)d_in[1];   // (2, 16)
  const float* b1  = (const float*)d_in[2];   // (16,)
  const float* W2  = (const float*)d_in[3];   // (16, 1)
  // d_in[4] = b2 : unused by the reference computation
  float* out = (float*)d_out;                 // (B, T) f32

  Coef cf;
  fit_sigma_coeffs(6.5, cf);   // deterministic, host-only, runs at capture

  dim3 grid(B_ROWS / 4);   // 1024 waves = 1 per SIMD; wall = steps x chain
  dim3 block(64);
  hipLaunchKernelGGL(gsm_scan_kernel, grid, block, 0, stream,
                     inp, W1, b1, W2, out, cf);
}